// Round 14
// baseline (79.862 us; speedup 1.0000x reference)
//
#include <hip/hip_runtime.h>
#include <hip/hip_bf16.h>

typedef __bf16 bf16x8 __attribute__((ext_vector_type(8)));
typedef float f32x4 __attribute__((ext_vector_type(4)));
typedef unsigned short us8 __attribute__((ext_vector_type(8)));

#define MFMA16 __builtin_amdgcn_mfma_f32_16x16x32_bf16

__device__ __forceinline__ unsigned short f2bf(float f) {
    unsigned int u = __float_as_uint(f);
    u += 0x7fffu + ((u >> 16) & 1u);   // round-to-nearest-even
    return (unsigned short)(u >> 16);
}

__device__ __forceinline__ void gload_lds16(const void* g, void* l) {
    __builtin_amdgcn_global_load_lds(
        (const __attribute__((address_space(1))) unsigned int*)g,
        (__attribute__((address_space(3))) unsigned int*)l, 16, 0, 0);
}

// ============ Pass 1: weights ONLY -> packed B-hat (R,U,C) ============
// 3 panels of [nb 0..31][kb' 0..31] 1KB frags; kb'<16 from Wx_*, >=16 Wh_*.
// Frag layout: lane=(kk>>3)*16+col, 8 contig k per lane.
__global__ void cvt_w_kernel(const float* __restrict__ W0, const float* __restrict__ W1,
                             const float* __restrict__ W2, const float* __restrict__ W3,
                             const float* __restrict__ W4, const float* __restrict__ W5,
                             unsigned short* __restrict__ WP) {
    int c = blockIdx.x * 256 + threadIdx.x;   // 0..196607
    int s = c >> 16, c2 = c & 65535;
    int frag = c2 >> 6, lane = c2 & 63;
    int nb = frag >> 5, kbp = frag & 31;
    const float* Wsrc;
    int kb;
    if (kbp < 16) { kb = kbp;      Wsrc = (s == 0) ? W0 : (s == 1) ? W2 : W4; }
    else          { kb = kbp - 16; Wsrc = (s == 0) ? W1 : (s == 1) ? W3 : W5; }
    int cc = lane & 15, ko = lane >> 4;
    int kbase = kb * 32 + ko * 8;
    us8 o;
#pragma unroll
    for (int e = 0; e < 8; ++e)
        o[e] = f2bf(Wsrc[(size_t)(kbase + e) * 512 + nb * 16 + cc]);
    *((us8*)WP + c) = o;
}

// ============ Pass 2: fused GEMM + AUGRU epilogue, direct-fp32 A ============
// 4 waves (4M x 1N), wave 64r x 32c, block 256r x 32c, grid 512 = 2 blk/CU.
// A: x,h read fp32 directly (2 x dwordx4/frag) + v_cvt_pk_bf16_f32 in-reg.
// B: 3 panels double-buffered in 2 x 24KB LDS chunks (K'=128), gload_lds;
//    one __syncthreads per chunk (next-chunk stages issued a chunk earlier,
//    so the barrier's vmcnt(0) drain costs ~nothing).
// Budget: acc 128 (AGPR) + ~90 VGPR < 256 cap of launch_bounds(256,2).
__global__ __launch_bounds__(256, 2) void augru_mm(
    const float* __restrict__ x, const float* __restrict__ h,
    const unsigned short* __restrict__ WP_,   // 3 x 1 MiB packed (R,U,C)
    const float* __restrict__ b_r, const float* __restrict__ b_u, const float* __restrict__ b_h,
    const float* __restrict__ att, float* __restrict__ out) {
    __shared__ unsigned char sB[2][24576];    // [buf][g = s*8+nf*4+kbi][1KB]
    const unsigned char* __restrict__ WPb = (const unsigned char*)WP_;

    const int t0 = threadIdx.x, wv = t0 >> 6, lane = t0 & 63;
    const int laneoff = lane * 16;
    const int r = lane & 15, ko = lane >> 4;

    // bijective XCD swizzle: XCD x owns Wid [64x,64x+64) = 4 m-panels x 16 n
    const int bid = blockIdx.x;               // 0..511
    const int Wid = (bid & 7) * 64 + (bid >> 3);
    const int mblk = Wid >> 4, nblk = Wid & 15;

    f32x4 accR[4][2] = {}, accU[4][2] = {}, accXH[4][2] = {}, accHH[4][2] = {};

    // A fp32 bases: row = mblk*256 + wv*64 + mf*16 + r, col-chunk ko*8
    const float* __restrict__ pX[4];
    const float* __restrict__ pH[4];
#pragma unroll
    for (int mf = 0; mf < 4; ++mf) {
        size_t ro = (size_t)(mblk * 256 + wv * 64 + mf * 16 + r) * 512 + ko * 8;
        pX[mf] = x + ro;
        pH[mf] = h + ro;
    }

    // B staging: wave stages frags g = wv + 4i (i=0..5), 24 frags/chunk
    const unsigned char* wsrc[6];
    unsigned sdst[6];
#pragma unroll
    for (int i = 0; i < 6; ++i) {
        int g = wv + 4 * i, s = g >> 3, nf = (g >> 2) & 1, kbi = g & 3;
        wsrc[i] = WPb + (((size_t)(s * 1024 + (nblk * 2 + nf) * 32 + kbi)) << 10) + laneoff;
        sdst[i] = (unsigned)g << 10;
    }

#define STAGE(C, BI) { _Pragma("unroll") for (int i = 0; i < 6; ++i) \
        gload_lds16(wsrc[i] + ((size_t)(C) << 12), &sB[BI][sdst[i]]); }

#define CVT8(dst, p) { float4 v0_ = *(const float4*)(p); \
    float4 v1_ = *(const float4*)((p) + 4); \
    union { unsigned int u[4]; bf16x8 b; } R_; \
    asm("v_cvt_pk_bf16_f32 %0,%1,%2" : "=v"(R_.u[0]) : "v"(v0_.x), "v"(v0_.y)); \
    asm("v_cvt_pk_bf16_f32 %0,%1,%2" : "=v"(R_.u[1]) : "v"(v0_.z), "v"(v0_.w)); \
    asm("v_cvt_pk_bf16_f32 %0,%1,%2" : "=v"(R_.u[2]) : "v"(v1_.x), "v"(v1_.y)); \
    asm("v_cvt_pk_bf16_f32 %0,%1,%2" : "=v"(R_.u[3]) : "v"(v1_.z), "v"(v1_.w)); \
    dst = R_.b; }

    STAGE(0, 0)
    __syncthreads();                          // chunk-0 B ready

#pragma unroll
    for (int c = 0; c < 8; ++c) {             // chunks of K'=128 (4 kbi each)
        if (c < 7) STAGE(c + 1, (c + 1) & 1)
        const unsigned char* buf = sB[c & 1];
#pragma unroll
        for (int kbi = 0; kbi < 4; ++kbi) {
            // A frags (x for chunks 0-3, h for 4-7); k = ((c&3)*4+kbi)*32
            const int ke = ((c & 3) * 4 + kbi) * 32;
            bf16x8 a[4];
#pragma unroll
            for (int mf = 0; mf < 4; ++mf) {
                const float* pa = (c < 4) ? pX[mf] : pH[mf];
                CVT8(a[mf], pa + ke)
            }
            bf16x8 bR[2], bU[2], bC[2];
#pragma unroll
            for (int nf = 0; nf < 2; ++nf) {
                bR[nf] = *(const bf16x8*)(buf + ((0 * 8 + nf * 4 + kbi) << 10) + laneoff);
                bU[nf] = *(const bf16x8*)(buf + ((1 * 8 + nf * 4 + kbi) << 10) + laneoff);
                bC[nf] = *(const bf16x8*)(buf + ((2 * 8 + nf * 4 + kbi) << 10) + laneoff);
            }
            __builtin_amdgcn_s_setprio(1);
#pragma unroll
            for (int mf = 0; mf < 4; ++mf)
#pragma unroll
                for (int nf = 0; nf < 2; ++nf) {
                    accR[mf][nf] = MFMA16(a[mf], bR[nf], accR[mf][nf], 0, 0, 0);
                    accU[mf][nf] = MFMA16(a[mf], bU[nf], accU[mf][nf], 0, 0, 0);
                    if (c < 4) accXH[mf][nf] = MFMA16(a[mf], bC[nf], accXH[mf][nf], 0, 0, 0);
                    else       accHH[mf][nf] = MFMA16(a[mf], bC[nf], accHH[mf][nf], 0, 0, 0);
                }
            __builtin_amdgcn_s_setprio(0);
        }
        __syncthreads();                      // release buf for restage
    }

    // epilogue: C/D layout col=lane&15, row=(lane>>4)*4+reg  [m89-verified]
    const int lr = lane & 15, lg = lane >> 4;
#pragma unroll
    for (int nf = 0; nf < 2; ++nf) {
        const int col = nblk * 32 + nf * 16 + lr;
        const float br = b_r[col], bu = b_u[col], bh = b_h[col];
#pragma unroll
        for (int mf = 0; mf < 4; ++mf) {
            const int rowb = mblk * 256 + wv * 64 + mf * 16 + lg * 4;
#pragma unroll
            for (int q = 0; q < 4; ++q) {
                const int row = rowb + q;
                float rg = 1.f / (1.f + __expf(-(accR[mf][nf][q] + br)));
                float ug = 1.f / (1.f + __expf(-(accU[mf][nf][q] + bu)));
                float ph = accXH[mf][nf][q] + bh + rg * accHH[mf][nf][q];
                ph = fminf(fmaxf(ph, -15.f), 15.f);
                float e = __expf(2.f * ph);
                float cal = (e - 1.f) / (e + 1.f);
                float hv = h[(size_t)row * 512 + col];
                float ua = att[row] * ug;
                out[(size_t)row * 512 + col] = fmaf(ua, cal - hv, hv);
            }
        }
    }
#undef STAGE
#undef CVT8
}

extern "C" void kernel_launch(void* const* d_in, const int* in_sizes, int n_in,
                              void* d_out, int out_size, void* d_ws, size_t ws_size,
                              hipStream_t stream) {
    const float* x    = (const float*)d_in[0];
    const float* h    = (const float*)d_in[1];
    const float* att  = (const float*)d_in[2];
    const float* Wx_r = (const float*)d_in[3];
    const float* b_r  = (const float*)d_in[4];
    const float* Wh_r = (const float*)d_in[5];
    const float* Wx_u = (const float*)d_in[6];
    const float* b_u  = (const float*)d_in[7];
    const float* Wh_u = (const float*)d_in[8];
    const float* Wx_h = (const float*)d_in[9];
    const float* b_h  = (const float*)d_in[10];
    const float* Wh_h = (const float*)d_in[11];
    float* out = (float*)d_out;

    unsigned short* WP = (unsigned short*)d_ws;   // 3 MiB packed B-hat (R,U,C)

    cvt_w_kernel<<<768, 256, 0, stream>>>(Wx_r, Wh_r, Wx_u, Wh_u, Wx_h, Wh_h, WP);
    augru_mm<<<512, 256, 0, stream>>>(x, h, WP, b_r, b_u, b_h, att, out);
}

// Round 15
// 46.973 us; speedup vs baseline: 1.7002x; 1.7002x over previous
//
#include <hip/hip_runtime.h>
#include <hip/hip_bf16.h>

typedef __bf16 bf16x8 __attribute__((ext_vector_type(8)));
typedef float f32x4 __attribute__((ext_vector_type(4)));
typedef unsigned short us8 __attribute__((ext_vector_type(8)));

#define MFMA16 __builtin_amdgcn_mfma_f32_16x16x32_bf16

__device__ __forceinline__ unsigned short f2bf(float f) {
    unsigned int u = __float_as_uint(f);
    u += 0x7fffu + ((u >> 16) & 1u);   // round-to-nearest-even
    return (unsigned short)(u >> 16);
}

__device__ __forceinline__ void gload_lds16(const void* g, void* l) {
    __builtin_amdgcn_global_load_lds(
        (const __attribute__((address_space(1))) unsigned int*)g,
        (__attribute__((address_space(3))) unsigned int*)l, 16, 0, 0);
}

// ============ Pass 1 (fused): pack A' = [x | h] along K' and B-hat panels ====
// Frag = 1024 B = 16 rows x 32 k (lane=(kk>>3)*16+row, 8 contig k per lane).
// A': frag index = mb*32 + kb'  (kb' = kb for x, 16+kb for h), mb 0..511.
// B-hat: 3 buffers (R,U,C) of [nb 0..31][kb' 0..31] frags.
__global__ void cvt_all_kernel(const float* __restrict__ x, const float* __restrict__ h,
                               unsigned short* __restrict__ AP,
                               const float* __restrict__ W0, const float* __restrict__ W1,
                               const float* __restrict__ W2, const float* __restrict__ W3,
                               const float* __restrict__ W4, const float* __restrict__ W5,
                               unsigned short* __restrict__ WP) {
    if (blockIdx.x < 4096) {                         // x,h -> A'
        int c = blockIdx.x * 256 + threadIdx.x;      // 0 .. 2^20-1
        int ih = c >> 19;
        const float* src = ih ? h : x;
        int c2 = c & 524287;
        int mb = c2 >> 10, kb = (c2 >> 6) & 15, lane = c2 & 63;
        int r = lane & 15, ko = lane >> 4;
        const float* p = src + (size_t)(mb * 16 + r) * 512 + kb * 32 + ko * 8;
        float4 v0 = *(const float4*)p;
        float4 v1 = *(const float4*)(p + 4);
        us8 o = { f2bf(v0.x), f2bf(v0.y), f2bf(v0.z), f2bf(v0.w),
                  f2bf(v1.x), f2bf(v1.y), f2bf(v1.z), f2bf(v1.w) };
        *((us8*)AP + ((size_t)(mb * 32 + kb + ih * 16) << 6) + lane) = o;
    } else {                                          // weights -> B-hat
        int c = (blockIdx.x - 4096) * 256 + threadIdx.x;   // 0..196607
        int s = c >> 16, c2 = c & 65535;
        int frag = c2 >> 6, lane = c2 & 63;
        int nb = frag >> 5, kbp = frag & 31;
        const float* Wsrc;
        int kb;
        if (kbp < 16) { kb = kbp;      Wsrc = (s == 0) ? W0 : (s == 1) ? W2 : W4; }
        else          { kb = kbp - 16; Wsrc = (s == 0) ? W1 : (s == 1) ? W3 : W5; }
        int cc = lane & 15, ko = lane >> 4;
        int kbase = kb * 32 + ko * 8;
        us8 o;
#pragma unroll
        for (int e = 0; e < 8; ++e)
            o[e] = f2bf(Wsrc[(size_t)(kbase + e) * 512 + nb * 16 + cc]);
        *((us8*)WP + c) = o;
    }
}

// ============ Pass 2: fused GEMM + AUGRU — A in regs, B-only LDS ============
// R4's pipeline discipline x R7's geometry. 8 waves (4M x 2N), wave 64r x 32c,
// block 256r x 64c, BK=64, 16 K-tiles. Per tile per wave: 3 B gload_lds +
// 8 A global->reg (named 2-deep sets) + 12 B ds_reads + 48 MFMA.
// Barrier: s_waitcnt vmcnt(8) + s_barrier (retires exactly the 3 B-stages;
// A loads stay in flight; compiler inserts exact waits for A-reg uses).
// LDS read/CU/tile: 96 KB (~1130 cyc) < MFMA budget 1862 cyc — the round-15
// change that breaks R6/R7's LDS-read co-limit (160 KB ~ 1930 cyc).
__global__ __launch_bounds__(512, 2) void augru_mm(
    const unsigned short* __restrict__ AP_,
    const unsigned short* __restrict__ WP_,   // 3 x 1 MiB (R,U,C)
    const float* __restrict__ b_r, const float* __restrict__ b_u, const float* __restrict__ b_h,
    const float* __restrict__ att, const float* __restrict__ h32,
    float* __restrict__ out) {
    __shared__ unsigned char sB[2][24576];
    const unsigned char* __restrict__ APb = (const unsigned char*)AP_;
    const unsigned char* __restrict__ WPb = (const unsigned char*)WP_;

    const int t = threadIdx.x, wv = t >> 6, lane = t & 63;
    const size_t laneoff = (size_t)lane * 16;

    // bijective XCD swizzle: XCD x owns Wid in [32x, 32x+32) -> 4 m-panels
    const int bid = blockIdx.x;                 // 0..255
    const int Wid = (bid & 7) * 32 + (bid >> 3);
    const int mblk = Wid >> 3, nblk = Wid & 7;  // 32 m-panels x 8 n-panels
    const int wr = wv >> 1, wc = wv & 1;        // 4M x 2N wave grid

    f32x4 accR[4][2] = {}, accU[4][2] = {}, accXH[4][2] = {}, accHH[4][2] = {};

    // A: wave-private rows, global->reg; frag (mb, kb'=tile*2+kq)
    const unsigned char* __restrict__ gA[4];
#pragma unroll
    for (int mf = 0; mf < 4; ++mf)
        gA[mf] = APb + ((size_t)((mblk * 16 + wr * 4 + mf) * 32) << 10) + laneoff;

    // B staging: wave stages frags g = i*8 + wv (i=0..2), 24 frags/tile
    const unsigned char* gB[3];
    unsigned sdst[3];
#pragma unroll
    for (int i = 0; i < 3; ++i) {
        int g = i * 8 + wv, s = g >> 3, nbL = (g & 7) >> 1, kq = g & 1;
        gB[i] = WPb + (size_t)s * 1048576 +
                ((size_t)((nblk * 4 + nbL) * 32 + kq) << 10) + laneoff;
        sdst[i] = (unsigned)g << 10;
    }

#define STAGE_B(TT, BI) { _Pragma("unroll") for (int i = 0; i < 3; ++i) \
        gload_lds16(gB[i] + ((size_t)((TT) * 2) << 10), &sB[BI][sdst[i]]); }

#define LOAD_A(TT, AS) { _Pragma("unroll") for (int mf = 0; mf < 4; ++mf) \
        _Pragma("unroll") for (int kq = 0; kq < 2; ++kq) \
            AS[mf][kq] = *(const bf16x8*)(gA[mf] + ((size_t)((TT) * 2 + kq) << 10)); }

// counted barrier: retire the 3 B-stages (oldest), keep 8 A-loads in flight
#define BARRIER8 asm volatile("s_waitcnt vmcnt(8)\n\ts_barrier" ::: "memory");

#define DO_MFMA(BI, AS, ACCC) { \
    _Pragma("unroll") for (int kq = 0; kq < 2; ++kq) { \
        bf16x8 bR[2], bU[2], bC[2]; \
        _Pragma("unroll") for (int nf = 0; nf < 2; ++nf) { \
            bR[nf] = *(const bf16x8*)&sB[BI][((0 * 8 + (wc * 2 + nf) * 2 + kq) << 10) + laneoff]; \
            bU[nf] = *(const bf16x8*)&sB[BI][((1 * 8 + (wc * 2 + nf) * 2 + kq) << 10) + laneoff]; \
            bC[nf] = *(const bf16x8*)&sB[BI][((2 * 8 + (wc * 2 + nf) * 2 + kq) << 10) + laneoff]; } \
        __builtin_amdgcn_s_setprio(1); \
        _Pragma("unroll") for (int mf = 0; mf < 4; ++mf) \
            _Pragma("unroll") for (int nf = 0; nf < 2; ++nf) { \
                accR[mf][nf] = MFMA16(AS[mf][kq], bR[nf], accR[mf][nf], 0, 0, 0); \
                accU[mf][nf] = MFMA16(AS[mf][kq], bU[nf], accU[mf][nf], 0, 0, 0); \
                ACCC[mf][nf] = MFMA16(AS[mf][kq], bC[nf], ACCC[mf][nf], 0, 0, 0); } \
        __builtin_amdgcn_s_setprio(0); } }

    bf16x8 a0[4][2], a1[4][2];

    // prologue
    STAGE_B(0, 0)
    LOAD_A(0, a0)
    BARRIER8

#pragma unroll 1
    for (int it = 0; it < 4; ++it) {            // tiles 0..7: x-half -> accXH
        const int tt = it * 2;
        STAGE_B(tt + 1, 1) LOAD_A(tt + 1, a1)
        DO_MFMA(0, a0, accXH)
        BARRIER8
        STAGE_B(tt + 2, 0) LOAD_A(tt + 2, a0)
        DO_MFMA(1, a1, accXH)
        BARRIER8
    }
#pragma unroll 1
    for (int it = 4; it < 7; ++it) {            // tiles 8..13: h-half -> accHH
        const int tt = it * 2;
        STAGE_B(tt + 1, 1) LOAD_A(tt + 1, a1)
        DO_MFMA(0, a0, accHH)
        BARRIER8
        STAGE_B(tt + 2, 0) LOAD_A(tt + 2, a0)
        DO_MFMA(1, a1, accHH)
        BARRIER8
    }
    STAGE_B(15, 1) LOAD_A(15, a1)               // tile 14
    DO_MFMA(0, a0, accHH)
    BARRIER8
    DO_MFMA(1, a1, accHH)                       // tile 15 (compiler waits A/lds)

    // epilogue: C/D layout col=lane&15, row=(lane>>4)*4+reg  [m89-verified]
    const int lr = lane & 15, lg = lane >> 4;
#pragma unroll
    for (int nf = 0; nf < 2; ++nf) {
        const int col = nblk * 64 + wc * 32 + nf * 16 + lr;
        const float br = b_r[col], bu = b_u[col], bh = b_h[col];
#pragma unroll
        for (int mf = 0; mf < 4; ++mf) {
            const int rowb = mblk * 256 + wr * 64 + mf * 16 + lg * 4;
#pragma unroll
            for (int q = 0; q < 4; ++q) {
                const int row = rowb + q;
                float r = 1.f / (1.f + __expf(-(accR[mf][nf][q] + br)));
                float u = 1.f / (1.f + __expf(-(accU[mf][nf][q] + bu)));
                float ph = accXH[mf][nf][q] + bh + r * accHH[mf][nf][q];
                ph = fminf(fmaxf(ph, -15.f), 15.f);
                float e = __expf(2.f * ph);
                float cal = (e - 1.f) / (e + 1.f);
                float hv = h32[(size_t)row * 512 + col];
                float ua = att[row] * u;
                out[(size_t)row * 512 + col] = fmaf(ua, cal - hv, hv);
            }
        }
    }
#undef STAGE_B
#undef LOAD_A
#undef BARRIER8
#undef DO_MFMA
}

extern "C" void kernel_launch(void* const* d_in, const int* in_sizes, int n_in,
                              void* d_out, int out_size, void* d_ws, size_t ws_size,
                              hipStream_t stream) {
    const float* x    = (const float*)d_in[0];
    const float* h    = (const float*)d_in[1];
    const float* att  = (const float*)d_in[2];
    const float* Wx_r = (const float*)d_in[3];
    const float* b_r  = (const float*)d_in[4];
    const float* Wh_r = (const float*)d_in[5];
    const float* Wx_u = (const float*)d_in[6];
    const float* b_u  = (const float*)d_in[7];
    const float* Wh_u = (const float*)d_in[8];
    const float* Wx_h = (const float*)d_in[9];
    const float* b_h  = (const float*)d_in[10];
    const float* Wh_h = (const float*)d_in[11];
    float* out = (float*)d_out;

    unsigned short* AP = (unsigned short*)d_ws;   // 16 MiB packed [x|h]
    unsigned short* WP = AP + 8388608;            //  3 MiB packed B-hat (R,U,C)

    cvt_all_kernel<<<4864, 256, 0, stream>>>(x, h, AP,
        Wx_r, Wh_r, Wx_u, Wh_u, Wx_h, Wh_h, WP);
    augru_mm<<<256, 512, 0, stream>>>(AP, WP, b_r, b_u, b_h, att, h, out);
}